// Round 8
// baseline (214.725 us; speedup 1.0000x reference)
//
#include <hip/hip_runtime.h>
#include <hip/hip_bf16.h>
#include <cmath>

#define D_MODEL 1024
#define N_HEADS 16
#define HEAD_DIM 64
#define SEQ 2048
#define BATCH 2
#define MROWS (BATCH * SEQ)  // 4096

typedef __bf16 bf16;
typedef __bf16 bf16x8 __attribute__((ext_vector_type(8)));
typedef __bf16 bf16x4 __attribute__((ext_vector_type(4)));
typedef float f32x4 __attribute__((ext_vector_type(4)));

// GEMM LDS swizzle (64B rows)
#define SWZG(row, cbyte) ((row) * 64 + ((cbyte) ^ ((((row) >> 1) & 3) << 4)))

// ---------------- fp32 -> bf16 convert (x) ----------------
__global__ __launch_bounds__(256) void cvt_x(const float* __restrict__ x,
                                             bf16* __restrict__ xb) {
    int i = blockIdx.x * 256 + threadIdx.x;
    float4 v = ((const float4*)x)[i];
    bf16x4 o = { (bf16)v.x, (bf16)v.y, (bf16)v.z, (bf16)v.w };
    ((bf16x4*)xb)[i] = o;
}

// ---------------- weight transpose + convert: wt[z][n][k] = W_z[k][n] ----------------
__global__ void cvt_wt(const float* __restrict__ Wq, const float* __restrict__ Wk,
                       const float* __restrict__ Wv, const float* __restrict__ Wo,
                       bf16* __restrict__ wt) {
    __shared__ float tile[32][33];
    int z = blockIdx.z;
    const float* W = (z == 0) ? Wq : (z == 1) ? Wk : (z == 2) ? Wv : Wo;
    int n0 = blockIdx.x * 32, k0 = blockIdx.y * 32;
    int tx = threadIdx.x, ty = threadIdx.y;
    tile[ty][tx] = W[(size_t)(k0 + ty) * D_MODEL + n0 + tx];
    __syncthreads();
    wt[(size_t)z * D_MODEL * D_MODEL + (size_t)(n0 + ty) * D_MODEL + k0 + tx] =
        (bf16)tile[tx][ty];
}

// ---------------- GEMM: Y[M,N] = A[M,K] @ Wt[N,K]^T + bias ----------------
// MODE 0: fused QKV, N = 3072. z=0 -> Q[bh][t][d], z=1 -> K[bh][t][d],
//         z=2 -> V^T[bh][d][t]  (transposed here so attention loads B-frags direct).
// MODE 1: out proj, N = 1024, f32 out [M, N].
template <int MODE>
__global__ __launch_bounds__(256) void gemm_k(const bf16* __restrict__ A,
                                              const bf16* __restrict__ Bt,
                                              const float* __restrict__ b0,
                                              const float* __restrict__ b1,
                                              const float* __restrict__ b2,
                                              void* __restrict__ outp) {
    constexpr int BM = 128, BK = 32, KDIM = D_MODEL;
    __shared__ alignas(16) bf16 As[BM * BK];
    __shared__ alignas(16) bf16 Bs[BM * BK];
    char* Asb = (char*)As;
    char* Bsb = (char*)Bs;
    const int tid = threadIdx.x;
    const int wid = tid >> 6, lane = tid & 63;
    const int m0 = blockIdx.y * BM, n0 = blockIdx.x * BM;
    const int wr = (wid >> 1) * 64, wc = (wid & 1) * 64;
    f32x4 acc[4][4] = {};

    for (int k0 = 0; k0 < KDIM; k0 += BK) {
        __syncthreads();
#pragma unroll
        for (int c = 0; c < 2; ++c) {
            int idx = tid + c * 256;
            int row = idx >> 2, cb = (idx & 3) * 16;
            *(bf16x8*)(Asb + SWZG(row, cb)) =
                *(const bf16x8*)&A[(size_t)(m0 + row) * KDIM + k0 + (cb >> 1)];
            *(bf16x8*)(Bsb + SWZG(row, cb)) =
                *(const bf16x8*)&Bt[(size_t)(n0 + row) * KDIM + k0 + (cb >> 1)];
        }
        __syncthreads();
        const int cb = (lane >> 4) * 16;
        bf16x8 a[4], b[4];
#pragma unroll
        for (int m = 0; m < 4; ++m) {
            int r = wr + m * 16 + (lane & 15);
            a[m] = *(bf16x8*)(Asb + SWZG(r, cb));
        }
#pragma unroll
        for (int n = 0; n < 4; ++n) {
            int r = wc + n * 16 + (lane & 15);
            b[n] = *(bf16x8*)(Bsb + SWZG(r, cb));
        }
#pragma unroll
        for (int m = 0; m < 4; ++m)
#pragma unroll
            for (int n = 0; n < 4; ++n)
                acc[m][n] = __builtin_amdgcn_mfma_f32_16x16x32_bf16(a[m], b[n], acc[m][n], 0, 0, 0);
    }

    const int z = n0 >> 10;  // block-uniform
    const float* bias = (MODE == 1) ? b0 : ((z == 0) ? b0 : (z == 1) ? b1 : b2);
#pragma unroll
    for (int m = 0; m < 4; ++m)
#pragma unroll
        for (int n = 0; n < 4; ++n)
#pragma unroll
            for (int r = 0; r < 4; ++r) {
                int grow = m0 + wr + m * 16 + (lane >> 4) * 4 + r;
                int gcol = n0 + wc + n * 16 + (lane & 15);
                if (MODE == 0) {
                    int colN = gcol & 1023;
                    float val = acc[m][n][r] + bias[colN];
                    int b_ = grow >> 11, s_ = grow & 2047;
                    int h = colN >> 6, hd = colN & 63;
                    if (z == 2) {
                        // V^T[bh][hd][t]
                        ((bf16*)outp)[(size_t)z * 4194304 +
                                      ((size_t)(b_ * N_HEADS + h) * HEAD_DIM + hd) * SEQ + s_] =
                            (bf16)val;
                    } else {
                        ((bf16*)outp)[(size_t)z * 4194304 +
                                      ((size_t)(b_ * N_HEADS + h) * SEQ + s_) * HEAD_DIM + hd] =
                            (bf16)val;
                    }
                } else {
                    float val = acc[m][n][r] + bias[gcol];
                    ((float*)outp)[(size_t)grow * D_MODEL + gcol] = val;
                }
            }
}

// ---------------- flash-style causal attention, barrier-free, high-TLP ----------------
// grid 1024 blocks x 256 threads (4 independent waves). Each wave owns one
// 16-row q-block of one (b,h): 4096 waves total. K/V^T B-fragments loaded
// directly from global (L2-resident); K register-double-buffered (prefetch
// next tile before current QK^T). No __syncthreads; wave-private P via LDS.
// Heavy-first: j = 127 - (p*4+wid) so longest q-blocks launch earliest.
__global__ __launch_bounds__(256) void attn_k(const bf16* __restrict__ Qg,
                                              const bf16* __restrict__ Kg,
                                              const bf16* __restrict__ VTg,
                                              bf16* __restrict__ AO) {
    __shared__ alignas(16) bf16 Ps[4][16 * 64];
    const int tid = threadIdx.x, wid = tid >> 6, lane = tid & 63;
    const int m = lane & 15, h = lane >> 4;
    const int p = blockIdx.x >> 5;    // 0..31
    const int bh = blockIdx.x & 31;
    const int j = 127 - (p * 4 + wid);  // 0..127, heavy first
    const int q0 = j * 16;
    const size_t base = (size_t)bh * SEQ * HEAD_DIM;
    const bf16* VT = VTg + (size_t)bh * HEAD_DIM * SEQ;
    char* Psb = (char*)&Ps[wid][0];

    // Q A-fragments: lane supplies Q[q0+m][kc*32 + h*8 + jj]
    bf16x8 aq[2];
#pragma unroll
    for (int kc = 0; kc < 2; ++kc)
        aq[kc] = *(const bf16x8*)&Qg[base + (size_t)(q0 + m) * HEAD_DIM + kc * 32 + h * 8];

    f32x4 o[4] = {};
    float mrow[4], lrow[4];
#pragma unroll
    for (int r = 0; r < 4; ++r) { mrow[r] = -__builtin_inff(); lrow[r] = 0.f; }

    const int nt = (j >> 2) + 1;
    bf16x8 kfA[4][2], kfB[4][2], vf[4][2];

#define LOADK(dst, t0v)                                                              \
    {                                                                                \
        _Pragma("unroll") for (int tf = 0; tf < 4; ++tf)                             \
            _Pragma("unroll") for (int kc = 0; kc < 2; ++kc)                         \
                dst[tf][kc] = *(const bf16x8*)&Kg[base +                             \
                    (size_t)((t0v) + tf * 16 + m) * HEAD_DIM + kc * 32 + h * 8];     \
    }

#define BODY(CUR, NXT)                                                               \
    {                                                                                \
        const int t0 = it * 64;                                                      \
        _Pragma("unroll") for (int nf = 0; nf < 4; ++nf)                             \
            _Pragma("unroll") for (int kc = 0; kc < 2; ++kc)                         \
                vf[nf][kc] = *(const bf16x8*)&VT[(size_t)(nf * 16 + m) * SEQ +       \
                                                 t0 + kc * 32 + h * 8];              \
        if (it + 1 < nt) LOADK(NXT, t0 + 64);                                        \
        f32x4 s[4];                                                                  \
        __builtin_amdgcn_s_setprio(1);                                               \
        _Pragma("unroll") for (int tf = 0; tf < 4; ++tf) {                           \
            f32x4 z = {};                                                            \
            z = __builtin_amdgcn_mfma_f32_16x16x32_bf16(aq[0], CUR[tf][0], z, 0, 0, 0); \
            z = __builtin_amdgcn_mfma_f32_16x16x32_bf16(aq[1], CUR[tf][1], z, 0, 0, 0); \
            s[tf] = z;                                                               \
        }                                                                            \
        __builtin_amdgcn_s_setprio(0);                                               \
        _Pragma("unroll") for (int tf = 0; tf < 4; ++tf)                             \
            _Pragma("unroll") for (int r = 0; r < 4; ++r) s[tf][r] *= 0.125f;        \
        if (it == nt - 1) {                                                          \
            _Pragma("unroll") for (int tf = 0; tf < 4; ++tf)                         \
                _Pragma("unroll") for (int r = 0; r < 4; ++r) {                      \
                    int gq = q0 + h * 4 + r;                                         \
                    int gt = t0 + tf * 16 + m;                                       \
                    if (gt > gq) s[tf][r] = -__builtin_inff();                       \
                }                                                                    \
        }                                                                            \
        float mx[4];                                                                 \
        _Pragma("unroll") for (int r = 0; r < 4; ++r)                                \
            mx[r] = fmaxf(fmaxf(s[0][r], s[1][r]), fmaxf(s[2][r], s[3][r]));         \
        _Pragma("unroll") for (int off = 1; off < 16; off <<= 1)                     \
            _Pragma("unroll") for (int r = 0; r < 4; ++r)                            \
                mx[r] = fmaxf(mx[r], __shfl_xor(mx[r], off));                        \
        float sf[4];                                                                 \
        _Pragma("unroll") for (int r = 0; r < 4; ++r) {                              \
            float mn = fmaxf(mrow[r], mx[r]);                                        \
            sf[r] = __expf(mrow[r] - mn);                                            \
            mrow[r] = mn;                                                            \
        }                                                                            \
        float rs[4] = {0.f, 0.f, 0.f, 0.f};                                          \
        _Pragma("unroll") for (int tf = 0; tf < 4; ++tf)                             \
            _Pragma("unroll") for (int r = 0; r < 4; ++r) {                          \
                float pv = __expf(s[tf][r] - mrow[r]);                               \
                s[tf][r] = pv;                                                       \
                rs[r] += pv;                                                         \
            }                                                                        \
        _Pragma("unroll") for (int off = 1; off < 16; off <<= 1)                     \
            _Pragma("unroll") for (int r = 0; r < 4; ++r)                            \
                rs[r] += __shfl_xor(rs[r], off);                                     \
        _Pragma("unroll") for (int r = 0; r < 4; ++r)                                \
            lrow[r] = lrow[r] * sf[r] + rs[r];                                       \
        _Pragma("unroll") for (int nf = 0; nf < 4; ++nf)                             \
            _Pragma("unroll") for (int r = 0; r < 4; ++r) o[nf][r] *= sf[r];         \
        _Pragma("unroll") for (int tf = 0; tf < 4; ++tf)                             \
            _Pragma("unroll") for (int r = 0; r < 4; ++r) {                          \
                int i = h * 4 + r;                                                   \
                int t = tf * 16 + m;                                                 \
                *(bf16*)(Psb + i * 128 + ((2 * t) ^ (h << 5))) = (bf16)s[tf][r];     \
            }                                                                        \
        __builtin_amdgcn_s_setprio(1);                                               \
        _Pragma("unroll") for (int kc = 0; kc < 2; ++kc) {                           \
            bf16x8 ap = *(bf16x8*)(Psb + m * 128 +                                   \
                                   ((2 * (kc * 32 + h * 8)) ^ ((m >> 2) << 5)));     \
            _Pragma("unroll") for (int nf = 0; nf < 4; ++nf)                         \
                o[nf] = __builtin_amdgcn_mfma_f32_16x16x32_bf16(                     \
                    ap, vf[nf][kc], o[nf], 0, 0, 0);                                 \
        }                                                                            \
        __builtin_amdgcn_s_setprio(0);                                               \
    }

    LOADK(kfA, 0);
    int it = 0;
    while (true) {
        BODY(kfA, kfB);
        if (++it >= nt) break;
        BODY(kfB, kfA);
        if (++it >= nt) break;
    }
#undef BODY
#undef LOADK

    const int b_ = bh >> 4, hh = bh & 15;
#pragma unroll
    for (int nf = 0; nf < 4; ++nf)
#pragma unroll
        for (int r = 0; r < 4; ++r) {
            int s_ = q0 + h * 4 + r;
            float val = o[nf][r] / lrow[r];
            AO[((size_t)(b_ * SEQ + s_)) * D_MODEL + hh * HEAD_DIM + nf * 16 + m] =
                (bf16)val;
        }
}

extern "C" void kernel_launch(void* const* d_in, const int* in_sizes, int n_in,
                              void* d_out, int out_size, void* d_ws, size_t ws_size,
                              hipStream_t stream) {
    const float* x  = (const float*)d_in[0];
    const float* Wq = (const float*)d_in[1];
    const float* bq = (const float*)d_in[2];
    const float* Wk = (const float*)d_in[3];
    const float* bk = (const float*)d_in[4];
    const float* Wv = (const float*)d_in[5];
    const float* bv = (const float*)d_in[6];
    const float* Wo = (const float*)d_in[7];
    const float* bo = (const float*)d_in[8];

    char* ws = (char*)d_ws;
    const size_t MB = 1u << 20;
    bf16* wt = (bf16*)ws;                  // 4 x [1024][1024] bf16 (QKV contiguous)
    bf16* xb = (bf16*)(ws + 8 * MB);       // [4096][1024] bf16
    bf16* Qb = (bf16*)(ws + 16 * MB);      // Q [32][2048][64]; K follows; then V^T [32][64][2048]
    bf16* AO = (bf16*)(ws + 40 * MB);      // [4096][1024] bf16

    const size_t WSTRIDE = (size_t)D_MODEL * D_MODEL;

    cvt_x<<<dim3(MROWS * D_MODEL / 4 / 256), dim3(256), 0, stream>>>(x, xb);
    cvt_wt<<<dim3(32, 32, 4), dim3(32, 32), 0, stream>>>(Wq, Wk, Wv, Wo, wt);

    // fused QKV projection: N = 3072 over contiguous [3072][1024] weight
    gemm_k<0><<<dim3(24, 32), dim3(256), 0, stream>>>(xb, wt, bq, bk, bv, Qb);

    bf16* Kb = Qb + 4194304;
    bf16* VTb = Qb + 2 * 4194304;
    attn_k<<<dim3(1024), dim3(256), 0, stream>>>(Qb, Kb, VTb, AO);

    gemm_k<1><<<dim3(8, 32), dim3(256), 0, stream>>>(AO, wt + 3 * WSTRIDE, bo, bo, bo, d_out);
}

// Round 10
// 153.127 us; speedup vs baseline: 1.4023x; 1.4023x over previous
//
#include <hip/hip_runtime.h>
#include <hip/hip_bf16.h>
#include <cmath>

#define D_MODEL 1024
#define N_HEADS 16
#define HEAD_DIM 64
#define SEQ 2048
#define BATCH 2
#define MROWS (BATCH * SEQ)  // 4096

typedef __bf16 bf16;
typedef __bf16 bf16x8 __attribute__((ext_vector_type(8)));
typedef __bf16 bf16x4 __attribute__((ext_vector_type(4)));
typedef float f32x4 __attribute__((ext_vector_type(4)));

// GEMM LDS swizzle (64B rows)
#define SWZG(row, cbyte) ((row) * 64 + ((cbyte) ^ ((((row) >> 1) & 3) << 4)))

// ---------------- fp32 -> bf16 convert (x) ----------------
__global__ __launch_bounds__(256) void cvt_x(const float* __restrict__ x,
                                             bf16* __restrict__ xb) {
    int i = blockIdx.x * 256 + threadIdx.x;
    float4 v = ((const float4*)x)[i];
    bf16x4 o = { (bf16)v.x, (bf16)v.y, (bf16)v.z, (bf16)v.w };
    ((bf16x4*)xb)[i] = o;
}

// ---------------- weight transpose + convert: wt[z][n][k] = W_z[k][n] ----------------
__global__ void cvt_wt(const float* __restrict__ Wq, const float* __restrict__ Wk,
                       const float* __restrict__ Wv, const float* __restrict__ Wo,
                       bf16* __restrict__ wt) {
    __shared__ float tile[32][33];
    int z = blockIdx.z;
    const float* W = (z == 0) ? Wq : (z == 1) ? Wk : (z == 2) ? Wv : Wo;
    int n0 = blockIdx.x * 32, k0 = blockIdx.y * 32;
    int tx = threadIdx.x, ty = threadIdx.y;
    tile[ty][tx] = W[(size_t)(k0 + ty) * D_MODEL + n0 + tx];
    __syncthreads();
    wt[(size_t)z * D_MODEL * D_MODEL + (size_t)(n0 + ty) * D_MODEL + k0 + tx] =
        (bf16)tile[tx][ty];
}

// ---------------- GEMM: Y[M,N] = A[M,K] @ Wt[N,K]^T + bias ----------------
// MODE 0: fused QKV, N = 3072. z=0 -> Q[bh][t][d], z=1 -> K[bh][t][d],
//         z=2 -> V^T[bh][d][t].  MODE 1: out proj, f32 out [M, N].
template <int MODE>
__global__ __launch_bounds__(256) void gemm_k(const bf16* __restrict__ A,
                                              const bf16* __restrict__ Bt,
                                              const float* __restrict__ b0,
                                              const float* __restrict__ b1,
                                              const float* __restrict__ b2,
                                              void* __restrict__ outp) {
    constexpr int BM = 128, BK = 32, KDIM = D_MODEL;
    __shared__ alignas(16) bf16 As[BM * BK];
    __shared__ alignas(16) bf16 Bs[BM * BK];
    char* Asb = (char*)As;
    char* Bsb = (char*)Bs;
    const int tid = threadIdx.x;
    const int wid = tid >> 6, lane = tid & 63;
    const int m0 = blockIdx.y * BM, n0 = blockIdx.x * BM;
    const int wr = (wid >> 1) * 64, wc = (wid & 1) * 64;
    f32x4 acc[4][4] = {};

    for (int k0 = 0; k0 < KDIM; k0 += BK) {
        __syncthreads();
#pragma unroll
        for (int c = 0; c < 2; ++c) {
            int idx = tid + c * 256;
            int row = idx >> 2, cb = (idx & 3) * 16;
            *(bf16x8*)(Asb + SWZG(row, cb)) =
                *(const bf16x8*)&A[(size_t)(m0 + row) * KDIM + k0 + (cb >> 1)];
            *(bf16x8*)(Bsb + SWZG(row, cb)) =
                *(const bf16x8*)&Bt[(size_t)(n0 + row) * KDIM + k0 + (cb >> 1)];
        }
        __syncthreads();
        const int cb = (lane >> 4) * 16;
        bf16x8 a[4], b[4];
#pragma unroll
        for (int m = 0; m < 4; ++m) {
            int r = wr + m * 16 + (lane & 15);
            a[m] = *(bf16x8*)(Asb + SWZG(r, cb));
        }
#pragma unroll
        for (int n = 0; n < 4; ++n) {
            int r = wc + n * 16 + (lane & 15);
            b[n] = *(bf16x8*)(Bsb + SWZG(r, cb));
        }
#pragma unroll
        for (int m = 0; m < 4; ++m)
#pragma unroll
            for (int n = 0; n < 4; ++n)
                acc[m][n] = __builtin_amdgcn_mfma_f32_16x16x32_bf16(a[m], b[n], acc[m][n], 0, 0, 0);
    }

    const int z = n0 >> 10;  // block-uniform
    const float* bias = (MODE == 1) ? b0 : ((z == 0) ? b0 : (z == 1) ? b1 : b2);
#pragma unroll
    for (int m = 0; m < 4; ++m)
#pragma unroll
        for (int n = 0; n < 4; ++n)
#pragma unroll
            for (int r = 0; r < 4; ++r) {
                int grow = m0 + wr + m * 16 + (lane >> 4) * 4 + r;
                int gcol = n0 + wc + n * 16 + (lane & 15);
                if (MODE == 0) {
                    int colN = gcol & 1023;
                    float val = acc[m][n][r] + bias[colN];
                    int b_ = grow >> 11, s_ = grow & 2047;
                    int h = colN >> 6, hd = colN & 63;
                    if (z == 2) {
                        ((bf16*)outp)[(size_t)z * 4194304 +
                                      ((size_t)(b_ * N_HEADS + h) * HEAD_DIM + hd) * SEQ + s_] =
                            (bf16)val;
                    } else {
                        ((bf16*)outp)[(size_t)z * 4194304 +
                                      ((size_t)(b_ * N_HEADS + h) * SEQ + s_) * HEAD_DIM + hd] =
                            (bf16)val;
                    }
                } else {
                    float val = acc[m][n][r] + bias[gcol];
                    ((float*)outp)[(size_t)grow * D_MODEL + gcol] = val;
                }
            }
}

// ---------------- flash attention, split-K pairs, barrier-once ----------------
// grid 512 blocks x 512 threads (8 waves = 4 q-block pairs). Each 32-row q-block
// is processed by TWO waves: half 0 -> KV tiles [0, nh0), half 1 -> [nh0, nt).
// Same traffic as the 32-row single-wave version (each KV tile read once per
// q-block) but 2x the waves (4096 = 4/SIMD). Halves merge m/l/o via LDS with a
// single __syncthreads. K/V^T fragments direct from L2; wave-private P in LDS.
// blockIdx = p*32 + bh: bh%8 fixes the XCD (L2 locality), p ascending = heavy first.
__global__ __launch_bounds__(512) void attn_k(const bf16* __restrict__ Qg,
                                              const bf16* __restrict__ Kg,
                                              const bf16* __restrict__ VTg,
                                              bf16* __restrict__ AO) {
    __shared__ alignas(16) bf16 Ps[8][2][16 * 64];   // 32 KB wave-private P
    __shared__ alignas(16) f32x4 Og[4][2][4][64];    // 32 KB merge: [pair][sub][nf][lane]
    __shared__ float Mg[4][2][4][64];                // 8 KB  [pair][sub][r][lane]
    __shared__ float Lg[4][2][4][64];                // 8 KB
    const int tid = threadIdx.x, wid = tid >> 6, lane = tid & 63;
    const int m = lane & 15, h = lane >> 4;
    const int pair = wid & 3, half = wid >> 2;
    const int p = blockIdx.x >> 5;      // 0..15
    const int bh = blockIdx.x & 31;
    const int j = 63 - (p * 4 + pair);  // 0..63, heavy first
    const int q0 = j * 32;
    const size_t base = (size_t)bh * SEQ * HEAD_DIM;
    const bf16* VT = VTg + (size_t)bh * HEAD_DIM * SEQ;

    // Q A-fragments: lane supplies Q[q0+sub*16+m][kc*32 + h*8 + jj]
    bf16x8 aq[2][2];
#pragma unroll
    for (int sub = 0; sub < 2; ++sub)
#pragma unroll
        for (int kc = 0; kc < 2; ++kc)
            aq[sub][kc] = *(const bf16x8*)
                &Qg[base + (size_t)(q0 + sub * 16 + m) * HEAD_DIM + kc * 32 + h * 8];

    f32x4 o[2][4] = {};
    float mrow[2][4], lrow[2][4];
#pragma unroll
    for (int sub = 0; sub < 2; ++sub)
#pragma unroll
        for (int r = 0; r < 4; ++r) { mrow[sub][r] = -__builtin_inff(); lrow[sub][r] = 0.f; }

    const int nt = (j >> 1) + 1;
    const int nh0 = (nt + 1) >> 1;
    const int itb = half ? nh0 : 0;
    const int ite = half ? nt : nh0;

    for (int it = itb; it < ite; ++it) {
        const int t0 = it * 64;

        // K B-fragments direct from L2
        bf16x8 kf[4][2];
#pragma unroll
        for (int tf = 0; tf < 4; ++tf)
#pragma unroll
            for (int kc = 0; kc < 2; ++kc)
                kf[tf][kc] = *(const bf16x8*)
                    &Kg[base + (size_t)(t0 + tf * 16 + m) * HEAD_DIM + kc * 32 + h * 8];

        // ---- QK^T ----
        f32x4 s[2][4];
        __builtin_amdgcn_s_setprio(1);
#pragma unroll
        for (int sub = 0; sub < 2; ++sub)
#pragma unroll
            for (int tf = 0; tf < 4; ++tf) {
                f32x4 z = {};
                z = __builtin_amdgcn_mfma_f32_16x16x32_bf16(aq[sub][0], kf[tf][0], z, 0, 0, 0);
                z = __builtin_amdgcn_mfma_f32_16x16x32_bf16(aq[sub][1], kf[tf][1], z, 0, 0, 0);
                s[sub][tf] = z;
            }
        __builtin_amdgcn_s_setprio(0);

        // V^T B-fragments (consumed after softmax -> latency hidden)
        bf16x8 vf[4][2];
#pragma unroll
        for (int nf = 0; nf < 4; ++nf)
#pragma unroll
            for (int kc = 0; kc < 2; ++kc)
                vf[nf][kc] = *(const bf16x8*)
                    &VT[(size_t)(nf * 16 + m) * SEQ + t0 + kc * 32 + h * 8];

#pragma unroll
        for (int sub = 0; sub < 2; ++sub)
#pragma unroll
            for (int tf = 0; tf < 4; ++tf)
#pragma unroll
                for (int r = 0; r < 4; ++r) s[sub][tf][r] *= 0.125f;
        if (it == nt - 1) {
#pragma unroll
            for (int sub = 0; sub < 2; ++sub)
#pragma unroll
                for (int tf = 0; tf < 4; ++tf)
#pragma unroll
                    for (int r = 0; r < 4; ++r) {
                        int gq = q0 + sub * 16 + h * 4 + r;
                        int gt = t0 + tf * 16 + m;
                        if (gt > gq) s[sub][tf][r] = -__builtin_inff();
                    }
        }

        // ---- online softmax with defer-max (T13, THR=8) ----
#pragma unroll
        for (int sub = 0; sub < 2; ++sub) {
            float mx[4];
#pragma unroll
            for (int r = 0; r < 4; ++r)
                mx[r] = fmaxf(fmaxf(s[sub][0][r], s[sub][1][r]),
                              fmaxf(s[sub][2][r], s[sub][3][r]));
#pragma unroll
            for (int off = 1; off < 16; off <<= 1)
#pragma unroll
                for (int r = 0; r < 4; ++r) mx[r] = fmaxf(mx[r], __shfl_xor(mx[r], off));
            bool ok = (mx[0] <= mrow[sub][0] + 8.f) && (mx[1] <= mrow[sub][1] + 8.f) &&
                      (mx[2] <= mrow[sub][2] + 8.f) && (mx[3] <= mrow[sub][3] + 8.f);
            if (!__all(ok)) {
#pragma unroll
                for (int r = 0; r < 4; ++r) {
                    float mn = fmaxf(mrow[sub][r], mx[r]);
                    float sf = __expf(mrow[sub][r] - mn);
                    mrow[sub][r] = mn;
                    lrow[sub][r] *= sf;
#pragma unroll
                    for (int nf = 0; nf < 4; ++nf) o[sub][nf][r] *= sf;
                }
            }
            float rs[4] = {0.f, 0.f, 0.f, 0.f};
#pragma unroll
            for (int tf = 0; tf < 4; ++tf)
#pragma unroll
                for (int r = 0; r < 4; ++r) {
                    float pv = __expf(s[sub][tf][r] - mrow[sub][r]);
                    s[sub][tf][r] = pv;
                    rs[r] += pv;
                }
#pragma unroll
            for (int off = 1; off < 16; off <<= 1)
#pragma unroll
                for (int r = 0; r < 4; ++r) rs[r] += __shfl_xor(rs[r], off);
#pragma unroll
            for (int r = 0; r < 4; ++r) lrow[sub][r] += rs[r];

            // P -> wave-private LDS
            char* Psb = (char*)&Ps[wid][sub][0];
#pragma unroll
            for (int tf = 0; tf < 4; ++tf)
#pragma unroll
                for (int r = 0; r < 4; ++r) {
                    int i = h * 4 + r;
                    int t = tf * 16 + m;
                    *(bf16*)(Psb + i * 128 + ((2 * t) ^ (h << 5))) = (bf16)s[sub][tf][r];
                }
        }

        // ---- PV ----
        __builtin_amdgcn_s_setprio(1);
#pragma unroll
        for (int sub = 0; sub < 2; ++sub) {
            char* Psb = (char*)&Ps[wid][sub][0];
#pragma unroll
            for (int kc = 0; kc < 2; ++kc) {
                bf16x8 ap = *(bf16x8*)(Psb + m * 128 +
                                       ((2 * (kc * 32 + h * 8)) ^ ((m >> 2) << 5)));
#pragma unroll
                for (int nf = 0; nf < 4; ++nf)
                    o[sub][nf] = __builtin_amdgcn_mfma_f32_16x16x32_bf16(
                        ap, vf[nf][kc], o[sub][nf], 0, 0, 0);
            }
        }
        __builtin_amdgcn_s_setprio(0);
    }

    // ---- split-K merge: half 1 publishes, half 0 combines & writes ----
    if (half == 1) {
#pragma unroll
        for (int sub = 0; sub < 2; ++sub) {
#pragma unroll
            for (int r = 0; r < 4; ++r) {
                Mg[pair][sub][r][lane] = mrow[sub][r];
                Lg[pair][sub][r][lane] = lrow[sub][r];
            }
#pragma unroll
            for (int nf = 0; nf < 4; ++nf) Og[pair][sub][nf][lane] = o[sub][nf];
        }
    }
    __syncthreads();
    if (half == 0) {
        const int b_ = bh >> 4, hh = bh & 15;
#pragma unroll
        for (int sub = 0; sub < 2; ++sub) {
            float a0[4], a1[4];
#pragma unroll
            for (int r = 0; r < 4; ++r) {
                float m1 = Mg[pair][sub][r][lane];
                float ms = fmaxf(mrow[sub][r], m1);
                a0[r] = __expf(mrow[sub][r] - ms);
                a1[r] = __expf(m1 - ms);
                lrow[sub][r] = lrow[sub][r] * a0[r] + Lg[pair][sub][r][lane] * a1[r];
            }
#pragma unroll
            for (int nf = 0; nf < 4; ++nf) {
                f32x4 o1 = Og[pair][sub][nf][lane];
#pragma unroll
                for (int r = 0; r < 4; ++r) {
                    float val = (o[sub][nf][r] * a0[r] + o1[r] * a1[r]) / lrow[sub][r];
                    int s_ = q0 + sub * 16 + h * 4 + r;
                    AO[((size_t)(b_ * SEQ + s_)) * D_MODEL + hh * HEAD_DIM + nf * 16 + m] =
                        (bf16)val;
                }
            }
        }
    }
}

extern "C" void kernel_launch(void* const* d_in, const int* in_sizes, int n_in,
                              void* d_out, int out_size, void* d_ws, size_t ws_size,
                              hipStream_t stream) {
    const float* x  = (const float*)d_in[0];
    const float* Wq = (const float*)d_in[1];
    const float* bq = (const float*)d_in[2];
    const float* Wk = (const float*)d_in[3];
    const float* bk = (const float*)d_in[4];
    const float* Wv = (const float*)d_in[5];
    const float* bv = (const float*)d_in[6];
    const float* Wo = (const float*)d_in[7];
    const float* bo = (const float*)d_in[8];

    char* ws = (char*)d_ws;
    const size_t MB = 1u << 20;
    bf16* wt = (bf16*)ws;                  // 4 x [1024][1024] bf16 (QKV contiguous)
    bf16* xb = (bf16*)(ws + 8 * MB);       // [4096][1024] bf16
    bf16* Qb = (bf16*)(ws + 16 * MB);      // Q [32][2048][64]; K; V^T [32][64][2048]
    bf16* AO = (bf16*)(ws + 40 * MB);      // [4096][1024] bf16

    const size_t WSTRIDE = (size_t)D_MODEL * D_MODEL;

    cvt_x<<<dim3(MROWS * D_MODEL / 4 / 256), dim3(256), 0, stream>>>(x, xb);
    cvt_wt<<<dim3(32, 32, 4), dim3(32, 32), 0, stream>>>(Wq, Wk, Wv, Wo, wt);

    gemm_k<0><<<dim3(24, 32), dim3(256), 0, stream>>>(xb, wt, bq, bk, bv, Qb);

    bf16* Kb = Qb + 4194304;
    bf16* VTb = Qb + 2 * 4194304;
    attn_k<<<dim3(512), dim3(512), 0, stream>>>(Qb, Kb, VTb, AO);

    gemm_k<1><<<dim3(8, 32), dim3(256), 0, stream>>>(AO, wt + 3 * WSTRIDE, bo, bo, bo, d_out);
}

// Round 12
// 151.921 us; speedup vs baseline: 1.4134x; 1.0079x over previous
//
#include <hip/hip_runtime.h>
#include <hip/hip_bf16.h>
#include <cmath>

#define D_MODEL 1024
#define N_HEADS 16
#define HEAD_DIM 64
#define SEQ 2048
#define BATCH 2
#define MROWS (BATCH * SEQ)  // 4096

typedef __bf16 bf16;
typedef __bf16 bf16x8 __attribute__((ext_vector_type(8)));
typedef __bf16 bf16x4 __attribute__((ext_vector_type(4)));
typedef float f32x4 __attribute__((ext_vector_type(4)));

// GEMM LDS swizzle (64B rows): byte = row*64 + (cbyte ^ (((row>>1)&3)<<4))
#define SWZG(row, cbyte) ((row) * 64 + ((cbyte) ^ ((((row) >> 1) & 3) << 4)))

// async global->LDS, 16B per lane, linear dest (wave base + lane*16)
#define GLOAD16(g, l)                                                        \
    __builtin_amdgcn_global_load_lds(                                        \
        (const __attribute__((address_space(1))) void*)(g),                  \
        (__attribute__((address_space(3))) void*)(l), 16, 0, 0)

// ---------------- fp32 -> bf16 convert (x) ----------------
__global__ __launch_bounds__(256) void cvt_x(const float* __restrict__ x,
                                             bf16* __restrict__ xb) {
    int i = blockIdx.x * 256 + threadIdx.x;
    float4 v = ((const float4*)x)[i];
    bf16x4 o = { (bf16)v.x, (bf16)v.y, (bf16)v.z, (bf16)v.w };
    ((bf16x4*)xb)[i] = o;
}

// ---------------- weight transpose + convert: wt[z][n][k] = W_z[k][n] ----------------
__global__ void cvt_wt(const float* __restrict__ Wq, const float* __restrict__ Wk,
                       const float* __restrict__ Wv, const float* __restrict__ Wo,
                       bf16* __restrict__ wt) {
    __shared__ float tile[32][33];
    int z = blockIdx.z;
    const float* W = (z == 0) ? Wq : (z == 1) ? Wk : (z == 2) ? Wv : Wo;
    int n0 = blockIdx.x * 32, k0 = blockIdx.y * 32;
    int tx = threadIdx.x, ty = threadIdx.y;
    tile[ty][tx] = W[(size_t)(k0 + ty) * D_MODEL + n0 + tx];
    __syncthreads();
    wt[(size_t)z * D_MODEL * D_MODEL + (size_t)(n0 + ty) * D_MODEL + k0 + tx] =
        (bf16)tile[tx][ty];
}

// ---------------- GEMM: Y[M,N] = A[M,K] @ Wt[N,K]^T + bias ----------------
// Staging via global_load_lds (16B/lane, linear LDS dest). Source address is
// inverse-swizzled per-lane so the linear write lands data where the SWZG
// reads expect it (rule: swizzle source+read, keep dest linear).
// MODE 0: fused QKV, N = 3072. z=0 -> Q[bh][t][d], z=1 -> K[bh][t][d],
//         z=2 -> V^T[bh][d][t].  MODE 1: out proj, f32 out [M, N].
template <int MODE>
__global__ __launch_bounds__(256) void gemm_k(const bf16* __restrict__ A,
                                              const bf16* __restrict__ Bt,
                                              const float* __restrict__ b0,
                                              const float* __restrict__ b1,
                                              const float* __restrict__ b2,
                                              void* __restrict__ outp) {
    constexpr int BM = 128, BK = 32, KDIM = D_MODEL;
    __shared__ alignas(16) bf16 As[BM * BK];
    __shared__ alignas(16) bf16 Bs[BM * BK];
    char* Asb = (char*)As;
    char* Bsb = (char*)Bs;
    const int tid = threadIdx.x;
    const int wid = tid >> 6, lane = tid & 63;
    const int m0 = blockIdx.y * BM, n0 = blockIdx.x * BM;
    const int wr = (wid >> 1) * 64, wc = (wid & 1) * 64;
    f32x4 acc[4][4] = {};

    for (int k0 = 0; k0 < KDIM; k0 += BK) {
        __syncthreads();
#pragma unroll
        for (int c = 0; c < 2; ++c) {
            const int q = c * 4 + wid;                // chunk 0..7 (wave-uniform)
            const int row = q * 16 + (lane >> 2);     // 0..127
            const int col = (lane & 3) ^ ((row >> 1) & 3);
            GLOAD16(&A[(size_t)(m0 + row) * KDIM + k0 + col * 8], Asb + q * 1024);
            GLOAD16(&Bt[(size_t)(n0 + row) * KDIM + k0 + col * 8], Bsb + q * 1024);
        }
        __syncthreads();  // compiler inserts vmcnt(0) before barrier
        const int cb = (lane >> 4) * 16;
        bf16x8 a[4], b[4];
#pragma unroll
        for (int m = 0; m < 4; ++m) {
            int r = wr + m * 16 + (lane & 15);
            a[m] = *(bf16x8*)(Asb + SWZG(r, cb));
        }
#pragma unroll
        for (int n = 0; n < 4; ++n) {
            int r = wc + n * 16 + (lane & 15);
            b[n] = *(bf16x8*)(Bsb + SWZG(r, cb));
        }
#pragma unroll
        for (int m = 0; m < 4; ++m)
#pragma unroll
            for (int n = 0; n < 4; ++n)
                acc[m][n] = __builtin_amdgcn_mfma_f32_16x16x32_bf16(a[m], b[n], acc[m][n], 0, 0, 0);
    }

    const int z = n0 >> 10;  // block-uniform
    const float* bias = (MODE == 1) ? b0 : ((z == 0) ? b0 : (z == 1) ? b1 : b2);
#pragma unroll
    for (int m = 0; m < 4; ++m)
#pragma unroll
        for (int n = 0; n < 4; ++n)
#pragma unroll
            for (int r = 0; r < 4; ++r) {
                int grow = m0 + wr + m * 16 + (lane >> 4) * 4 + r;
                int gcol = n0 + wc + n * 16 + (lane & 15);
                if (MODE == 0) {
                    int colN = gcol & 1023;
                    float val = acc[m][n][r] + bias[colN];
                    int b_ = grow >> 11, s_ = grow & 2047;
                    int h = colN >> 6, hd = colN & 63;
                    if (z == 2) {
                        ((bf16*)outp)[(size_t)z * 4194304 +
                                      ((size_t)(b_ * N_HEADS + h) * HEAD_DIM + hd) * SEQ + s_] =
                            (bf16)val;
                    } else {
                        ((bf16*)outp)[(size_t)z * 4194304 +
                                      ((size_t)(b_ * N_HEADS + h) * SEQ + s_) * HEAD_DIM + hd] =
                            (bf16)val;
                    }
                } else {
                    float val = acc[m][n][r] + bias[gcol];
                    ((float*)outp)[(size_t)grow * D_MODEL + gcol] = val;
                }
            }
}

// ---------------- flash attention, split-K pairs + K-prefetch ----------------
// grid 512 blocks x 512 threads (8 waves = 4 q-block pairs). Each 32-row q-block
// is processed by TWO waves: half 0 -> KV tiles [0, nh0), half 1 -> [nh0, nt).
// K fragments are PREFETCHED one tile ahead into the same registers (dead after
// QK^T issues) so L2 latency hides under softmax+PV. V^T fragments issued after
// QK^T, consumed after softmax. No barriers in the loop; one merge barrier.
__global__ __launch_bounds__(512) void attn_k(const bf16* __restrict__ Qg,
                                              const bf16* __restrict__ Kg,
                                              const bf16* __restrict__ VTg,
                                              bf16* __restrict__ AO) {
    __shared__ alignas(16) bf16 Ps[8][2][16 * 64];   // 32 KB wave-private P
    __shared__ alignas(16) f32x4 Og[4][2][4][64];    // 32 KB merge
    __shared__ float Mg[4][2][4][64];                // 8 KB
    __shared__ float Lg[4][2][4][64];                // 8 KB
    const int tid = threadIdx.x, wid = tid >> 6, lane = tid & 63;
    const int m = lane & 15, h = lane >> 4;
    const int pair = wid & 3, half = wid >> 2;
    const int p = blockIdx.x >> 5;      // 0..15
    const int bh = blockIdx.x & 31;
    const int j = 63 - (p * 4 + pair);  // 0..63, heavy first
    const int q0 = j * 32;
    const size_t base = (size_t)bh * SEQ * HEAD_DIM;
    const bf16* VT = VTg + (size_t)bh * HEAD_DIM * SEQ;

    bf16x8 aq[2][2];
#pragma unroll
    for (int sub = 0; sub < 2; ++sub)
#pragma unroll
        for (int kc = 0; kc < 2; ++kc)
            aq[sub][kc] = *(const bf16x8*)
                &Qg[base + (size_t)(q0 + sub * 16 + m) * HEAD_DIM + kc * 32 + h * 8];

    f32x4 o[2][4] = {};
    float mrow[2][4], lrow[2][4];
#pragma unroll
    for (int sub = 0; sub < 2; ++sub)
#pragma unroll
        for (int r = 0; r < 4; ++r) { mrow[sub][r] = -__builtin_inff(); lrow[sub][r] = 0.f; }

    const int nt = (j >> 1) + 1;
    const int nh0 = (nt + 1) >> 1;
    const int itb = half ? nh0 : 0;
    const int ite = half ? nt : nh0;

    // prologue: prefetch K for the first tile
    bf16x8 kf[4][2];
    if (itb < ite) {
        const int t0p = itb * 64;
#pragma unroll
        for (int tf = 0; tf < 4; ++tf)
#pragma unroll
            for (int kc = 0; kc < 2; ++kc)
                kf[tf][kc] = *(const bf16x8*)
                    &Kg[base + (size_t)(t0p + tf * 16 + m) * HEAD_DIM + kc * 32 + h * 8];
    }

    for (int it = itb; it < ite; ++it) {
        const int t0 = it * 64;

        // ---- QK^T (consumes kf) ----
        f32x4 s[2][4];
        __builtin_amdgcn_s_setprio(1);
#pragma unroll
        for (int sub = 0; sub < 2; ++sub)
#pragma unroll
            for (int tf = 0; tf < 4; ++tf) {
                f32x4 z = {};
                z = __builtin_amdgcn_mfma_f32_16x16x32_bf16(aq[sub][0], kf[tf][0], z, 0, 0, 0);
                z = __builtin_amdgcn_mfma_f32_16x16x32_bf16(aq[sub][1], kf[tf][1], z, 0, 0, 0);
                s[sub][tf] = z;
            }
        __builtin_amdgcn_s_setprio(0);

        // V^T fragments for the CURRENT tile (consumed after softmax)
        bf16x8 vf[4][2];
#pragma unroll
        for (int nf = 0; nf < 4; ++nf)
#pragma unroll
            for (int kc = 0; kc < 2; ++kc)
                vf[nf][kc] = *(const bf16x8*)
                    &VT[(size_t)(nf * 16 + m) * SEQ + t0 + kc * 32 + h * 8];

        // prefetch NEXT tile's K into the (now dead) kf registers
        if (it + 1 < ite) {
            const int t0n = t0 + 64;
#pragma unroll
            for (int tf = 0; tf < 4; ++tf)
#pragma unroll
                for (int kc = 0; kc < 2; ++kc)
                    kf[tf][kc] = *(const bf16x8*)
                        &Kg[base + (size_t)(t0n + tf * 16 + m) * HEAD_DIM + kc * 32 + h * 8];
        }

#pragma unroll
        for (int sub = 0; sub < 2; ++sub)
#pragma unroll
            for (int tf = 0; tf < 4; ++tf)
#pragma unroll
                for (int r = 0; r < 4; ++r) s[sub][tf][r] *= 0.125f;
        if (it == nt - 1) {
#pragma unroll
            for (int sub = 0; sub < 2; ++sub)
#pragma unroll
                for (int tf = 0; tf < 4; ++tf)
#pragma unroll
                    for (int r = 0; r < 4; ++r) {
                        int gq = q0 + sub * 16 + h * 4 + r;
                        int gt = t0 + tf * 16 + m;
                        if (gt > gq) s[sub][tf][r] = -__builtin_inff();
                    }
        }

        // ---- online softmax with defer-max (T13, THR=8) ----
#pragma unroll
        for (int sub = 0; sub < 2; ++sub) {
            float mx[4];
#pragma unroll
            for (int r = 0; r < 4; ++r)
                mx[r] = fmaxf(fmaxf(s[sub][0][r], s[sub][1][r]),
                              fmaxf(s[sub][2][r], s[sub][3][r]));
#pragma unroll
            for (int off = 1; off < 16; off <<= 1)
#pragma unroll
                for (int r = 0; r < 4; ++r) mx[r] = fmaxf(mx[r], __shfl_xor(mx[r], off));
            bool ok = (mx[0] <= mrow[sub][0] + 8.f) && (mx[1] <= mrow[sub][1] + 8.f) &&
                      (mx[2] <= mrow[sub][2] + 8.f) && (mx[3] <= mrow[sub][3] + 8.f);
            if (!__all(ok)) {
#pragma unroll
                for (int r = 0; r < 4; ++r) {
                    float mn = fmaxf(mrow[sub][r], mx[r]);
                    float sf = __expf(mrow[sub][r] - mn);
                    mrow[sub][r] = mn;
                    lrow[sub][r] *= sf;
#pragma unroll
                    for (int nf = 0; nf < 4; ++nf) o[sub][nf][r] *= sf;
                }
            }
            float rs[4] = {0.f, 0.f, 0.f, 0.f};
#pragma unroll
            for (int tf = 0; tf < 4; ++tf)
#pragma unroll
                for (int r = 0; r < 4; ++r) {
                    float pv = __expf(s[sub][tf][r] - mrow[sub][r]);
                    s[sub][tf][r] = pv;
                    rs[r] += pv;
                }
#pragma unroll
            for (int off = 1; off < 16; off <<= 1)
#pragma unroll
                for (int r = 0; r < 4; ++r) rs[r] += __shfl_xor(rs[r], off);
#pragma unroll
            for (int r = 0; r < 4; ++r) lrow[sub][r] += rs[r];

            // P -> wave-private LDS
            char* Psb = (char*)&Ps[wid][sub][0];
#pragma unroll
            for (int tf = 0; tf < 4; ++tf)
#pragma unroll
                for (int r = 0; r < 4; ++r) {
                    int i = h * 4 + r;
                    int t = tf * 16 + m;
                    *(bf16*)(Psb + i * 128 + ((2 * t) ^ (h << 5))) = (bf16)s[sub][tf][r];
                }
        }

        // ---- PV ----
        __builtin_amdgcn_s_setprio(1);
#pragma unroll
        for (int sub = 0; sub < 2; ++sub) {
            char* Psb = (char*)&Ps[wid][sub][0];
#pragma unroll
            for (int kc = 0; kc < 2; ++kc) {
                bf16x8 ap = *(bf16x8*)(Psb + m * 128 +
                                       ((2 * (kc * 32 + h * 8)) ^ ((m >> 2) << 5)));
#pragma unroll
                for (int nf = 0; nf < 4; ++nf)
                    o[sub][nf] = __builtin_amdgcn_mfma_f32_16x16x32_bf16(
                        ap, vf[nf][kc], o[sub][nf], 0, 0, 0);
            }
        }
        __builtin_amdgcn_s_setprio(0);
    }

    // ---- split-K merge: half 1 publishes, half 0 combines & writes ----
    if (half == 1) {
#pragma unroll
        for (int sub = 0; sub < 2; ++sub) {
#pragma unroll
            for (int r = 0; r < 4; ++r) {
                Mg[pair][sub][r][lane] = mrow[sub][r];
                Lg[pair][sub][r][lane] = lrow[sub][r];
            }
#pragma unroll
            for (int nf = 0; nf < 4; ++nf) Og[pair][sub][nf][lane] = o[sub][nf];
        }
    }
    __syncthreads();
    if (half == 0) {
        const int b_ = bh >> 4, hh = bh & 15;
#pragma unroll
        for (int sub = 0; sub < 2; ++sub) {
            float a0[4], a1[4];
#pragma unroll
            for (int r = 0; r < 4; ++r) {
                float m1 = Mg[pair][sub][r][lane];
                float ms = fmaxf(mrow[sub][r], m1);
                a0[r] = __expf(mrow[sub][r] - ms);
                a1[r] = __expf(m1 - ms);
                lrow[sub][r] = lrow[sub][r] * a0[r] + Lg[pair][sub][r][lane] * a1[r];
            }
#pragma unroll
            for (int nf = 0; nf < 4; ++nf) {
                f32x4 o1 = Og[pair][sub][nf][lane];
#pragma unroll
                for (int r = 0; r < 4; ++r) {
                    float val = (o[sub][nf][r] * a0[r] + o1[r] * a1[r]) / lrow[sub][r];
                    int s_ = q0 + sub * 16 + h * 4 + r;
                    AO[((size_t)(b_ * SEQ + s_)) * D_MODEL + hh * HEAD_DIM + nf * 16 + m] =
                        (bf16)val;
                }
            }
        }
    }
}

extern "C" void kernel_launch(void* const* d_in, const int* in_sizes, int n_in,
                              void* d_out, int out_size, void* d_ws, size_t ws_size,
                              hipStream_t stream) {
    const float* x  = (const float*)d_in[0];
    const float* Wq = (const float*)d_in[1];
    const float* bq = (const float*)d_in[2];
    const float* Wk = (const float*)d_in[3];
    const float* bk = (const float*)d_in[4];
    const float* Wv = (const float*)d_in[5];
    const float* bv = (const float*)d_in[6];
    const float* Wo = (const float*)d_in[7];
    const float* bo = (const float*)d_in[8];

    char* ws = (char*)d_ws;
    const size_t MB = 1u << 20;
    bf16* wt = (bf16*)ws;                  // 4 x [1024][1024] bf16 (QKV contiguous)
    bf16* xb = (bf16*)(ws + 8 * MB);       // [4096][1024] bf16
    bf16* Qb = (bf16*)(ws + 16 * MB);      // Q [32][2048][64]; K; V^T [32][64][2048]
    bf16* AO = (bf16*)(ws + 40 * MB);      // [4096][1024] bf16

    const size_t WSTRIDE = (size_t)D_MODEL * D_MODEL;

    cvt_x<<<dim3(MROWS * D_MODEL / 4 / 256), dim3(256), 0, stream>>>(x, xb);
    cvt_wt<<<dim3(32, 32, 4), dim3(32, 32), 0, stream>>>(Wq, Wk, Wv, Wo, wt);

    gemm_k<0><<<dim3(24, 32), dim3(256), 0, stream>>>(xb, wt, bq, bk, bv, Qb);

    bf16* Kb = Qb + 4194304;
    bf16* VTb = Qb + 2 * 4194304;
    attn_k<<<dim3(512), dim3(512), 0, stream>>>(Qb, Kb, VTb, AO);

    gemm_k<1><<<dim3(8, 32), dim3(256), 0, stream>>>(AO, wt + 3 * WSTRIDE, bo, bo, bo, d_out);
}

// Round 13
// 148.022 us; speedup vs baseline: 1.4506x; 1.0263x over previous
//
#include <hip/hip_runtime.h>
#include <hip/hip_bf16.h>
#include <cmath>

#define D_MODEL 1024
#define N_HEADS 16
#define HEAD_DIM 64
#define SEQ 2048
#define BATCH 2
#define MROWS (BATCH * SEQ)  // 4096

typedef __bf16 bf16;
typedef __bf16 bf16x8 __attribute__((ext_vector_type(8)));
typedef __bf16 bf16x4 __attribute__((ext_vector_type(4)));
typedef float f32x4 __attribute__((ext_vector_type(4)));

// GEMM LDS swizzle (64B rows): byte = row*64 + (cbyte ^ (((row>>1)&3)<<4))
#define SWZG(row, cbyte) ((row) * 64 + ((cbyte) ^ ((((row) >> 1) & 3) << 4)))

// async global->LDS, 16B per lane, linear dest (wave base + lane*16)
#define GLOAD16(g, l)                                                        \
    __builtin_amdgcn_global_load_lds(                                        \
        (const __attribute__((address_space(1))) void*)(g),                  \
        (__attribute__((address_space(3))) void*)(l), 16, 0, 0)

static __device__ __forceinline__ unsigned short bfbits(float f) {
    bf16 b = (bf16)f;
    return *(unsigned short*)&b;
}

// ---------------- fp32 -> bf16 convert (x) ----------------
__global__ __launch_bounds__(256) void cvt_x(const float* __restrict__ x,
                                             bf16* __restrict__ xb) {
    int i = blockIdx.x * 256 + threadIdx.x;
    float4 v = ((const float4*)x)[i];
    bf16x4 o = { (bf16)v.x, (bf16)v.y, (bf16)v.z, (bf16)v.w };
    ((bf16x4*)xb)[i] = o;
}

// ---------------- weight transpose + convert: wt[z][n][k] = W_z[k][n] ----------------
__global__ void cvt_wt(const float* __restrict__ Wq, const float* __restrict__ Wk,
                       const float* __restrict__ Wv, const float* __restrict__ Wo,
                       bf16* __restrict__ wt) {
    __shared__ float tile[32][33];
    int z = blockIdx.z;
    const float* W = (z == 0) ? Wq : (z == 1) ? Wk : (z == 2) ? Wv : Wo;
    int n0 = blockIdx.x * 32, k0 = blockIdx.y * 32;
    int tx = threadIdx.x, ty = threadIdx.y;
    tile[ty][tx] = W[(size_t)(k0 + ty) * D_MODEL + n0 + tx];
    __syncthreads();
    wt[(size_t)z * D_MODEL * D_MODEL + (size_t)(n0 + ty) * D_MODEL + k0 + tx] =
        (bf16)tile[tx][ty];
}

// ---------------- GEMM: Y[M,N] = A[M,K] @ Wt[N,K]^T + bias ----------------
template <int MODE>
__global__ __launch_bounds__(256) void gemm_k(const bf16* __restrict__ A,
                                              const bf16* __restrict__ Bt,
                                              const float* __restrict__ b0,
                                              const float* __restrict__ b1,
                                              const float* __restrict__ b2,
                                              void* __restrict__ outp) {
    constexpr int BM = 128, BK = 32, KDIM = D_MODEL;
    __shared__ alignas(16) bf16 As[BM * BK];
    __shared__ alignas(16) bf16 Bs[BM * BK];
    char* Asb = (char*)As;
    char* Bsb = (char*)Bs;
    const int tid = threadIdx.x;
    const int wid = tid >> 6, lane = tid & 63;
    const int m0 = blockIdx.y * BM, n0 = blockIdx.x * BM;
    const int wr = (wid >> 1) * 64, wc = (wid & 1) * 64;
    f32x4 acc[4][4] = {};

    for (int k0 = 0; k0 < KDIM; k0 += BK) {
        __syncthreads();
#pragma unroll
        for (int c = 0; c < 2; ++c) {
            const int q = c * 4 + wid;
            const int row = q * 16 + (lane >> 2);
            const int col = (lane & 3) ^ ((row >> 1) & 3);
            GLOAD16(&A[(size_t)(m0 + row) * KDIM + k0 + col * 8], Asb + q * 1024);
            GLOAD16(&Bt[(size_t)(n0 + row) * KDIM + k0 + col * 8], Bsb + q * 1024);
        }
        __syncthreads();
        const int cb = (lane >> 4) * 16;
        bf16x8 a[4], b[4];
#pragma unroll
        for (int m = 0; m < 4; ++m) {
            int r = wr + m * 16 + (lane & 15);
            a[m] = *(bf16x8*)(Asb + SWZG(r, cb));
        }
#pragma unroll
        for (int n = 0; n < 4; ++n) {
            int r = wc + n * 16 + (lane & 15);
            b[n] = *(bf16x8*)(Bsb + SWZG(r, cb));
        }
#pragma unroll
        for (int m = 0; m < 4; ++m)
#pragma unroll
            for (int n = 0; n < 4; ++n)
                acc[m][n] = __builtin_amdgcn_mfma_f32_16x16x32_bf16(a[m], b[n], acc[m][n], 0, 0, 0);
    }

    const int z = n0 >> 10;
    const float* bias = (MODE == 1) ? b0 : ((z == 0) ? b0 : (z == 1) ? b1 : b2);
#pragma unroll
    for (int m = 0; m < 4; ++m)
#pragma unroll
        for (int n = 0; n < 4; ++n)
#pragma unroll
            for (int r = 0; r < 4; ++r) {
                int grow = m0 + wr + m * 16 + (lane >> 4) * 4 + r;
                int gcol = n0 + wc + n * 16 + (lane & 15);
                if (MODE == 0) {
                    int colN = gcol & 1023;
                    float val = acc[m][n][r] + bias[colN];
                    int b_ = grow >> 11, s_ = grow & 2047;
                    int h = colN >> 6, hd = colN & 63;
                    if (z == 2) {
                        ((bf16*)outp)[(size_t)z * 4194304 +
                                      ((size_t)(b_ * N_HEADS + h) * HEAD_DIM + hd) * SEQ + s_] =
                            (bf16)val;
                    } else {
                        ((bf16*)outp)[(size_t)z * 4194304 +
                                      ((size_t)(b_ * N_HEADS + h) * SEQ + s_) * HEAD_DIM + hd] =
                            (bf16)val;
                    }
                } else {
                    float val = acc[m][n][r] + bias[gcol];
                    ((float*)outp)[(size_t)grow * D_MODEL + gcol] = val;
                }
            }
}

// ---------------- flash attention: split-K pairs + SWAPPED QK^T ----------------
// mfma(K,Q) instead of mfma(Q,K): identical fragments, transposed output.
// Lane (m,h) holds S[q=m][t=tf*16+h*4+r] -> row stats are per-lane scalars:
// reduce = 15 in-reg ops + 2 shuffles (vs 4 rounds x 4 regs before).
// P repacked to bf16x2 words in a small XOR-swizzled LDS buffer:
//   writer: word (t/2)^((m&7)<<2); reader b128 at ((16kc+4h)^((m&7)<<2)).
// Stats redistributed to o-row layout (q=h*4+r) via 4 shuffles only on
// rescale events (rare, defer-max) and once at the merge.
__global__ __launch_bounds__(512) void attn_k(const bf16* __restrict__ Qg,
                                              const bf16* __restrict__ Kg,
                                              const bf16* __restrict__ VTg,
                                              bf16* __restrict__ AO) {
    __shared__ alignas(16) unsigned int Pk[8][2][16][32];  // 32 KB packed P
    __shared__ alignas(16) f32x4 Og[4][2][4][64];          // 32 KB merge
    __shared__ float Mg[4][2][64];                         // 2 KB
    __shared__ float Lg[4][2][64];                         // 2 KB
    const int tid = threadIdx.x, wid = tid >> 6, lane = tid & 63;
    const int m = lane & 15, h = lane >> 4;
    const int pair = wid & 3, half = wid >> 2;
    const int p = blockIdx.x >> 5;
    const int bh = blockIdx.x & 31;
    const int j = 63 - (p * 4 + pair);  // heavy first
    const int q0 = j * 32;
    const size_t base = (size_t)bh * SEQ * HEAD_DIM;
    const bf16* VT = VTg + (size_t)bh * HEAD_DIM * SEQ;
    const int swz = (m & 7) << 2;

    bf16x8 aq[2][2];
#pragma unroll
    for (int sub = 0; sub < 2; ++sub)
#pragma unroll
        for (int kc = 0; kc < 2; ++kc)
            aq[sub][kc] = *(const bf16x8*)
                &Qg[base + (size_t)(q0 + sub * 16 + m) * HEAD_DIM + kc * 32 + h * 8];

    f32x4 o[2][4] = {};
    float mrow[2] = {-__builtin_inff(), -__builtin_inff()};
    float lrow[2] = {0.f, 0.f};

    const int nt = (j >> 1) + 1;
    const int nh0 = (nt + 1) >> 1;
    const int itb = half ? nh0 : 0;
    const int ite = half ? nt : nh0;

    bf16x8 kf[4][2];
    if (itb < ite) {
        const int t0p = itb * 64;
#pragma unroll
        for (int tf = 0; tf < 4; ++tf)
#pragma unroll
            for (int kc = 0; kc < 2; ++kc)
                kf[tf][kc] = *(const bf16x8*)
                    &Kg[base + (size_t)(t0p + tf * 16 + m) * HEAD_DIM + kc * 32 + h * 8];
    }

    for (int it = itb; it < ite; ++it) {
        const int t0 = it * 64;

        // ---- QK^T SWAPPED: D[t][q], lane holds q=m, t=tf*16+h*4+r ----
        f32x4 s[2][4];
        __builtin_amdgcn_s_setprio(1);
#pragma unroll
        for (int sub = 0; sub < 2; ++sub)
#pragma unroll
            for (int tf = 0; tf < 4; ++tf) {
                f32x4 z = {};
                z = __builtin_amdgcn_mfma_f32_16x16x32_bf16(kf[tf][0], aq[sub][0], z, 0, 0, 0);
                z = __builtin_amdgcn_mfma_f32_16x16x32_bf16(kf[tf][1], aq[sub][1], z, 0, 0, 0);
                s[sub][tf] = z;
            }
        __builtin_amdgcn_s_setprio(0);

        // V^T fragments (consumed after softmax)
        bf16x8 vf[4][2];
#pragma unroll
        for (int nf = 0; nf < 4; ++nf)
#pragma unroll
            for (int kc = 0; kc < 2; ++kc)
                vf[nf][kc] = *(const bf16x8*)
                    &VT[(size_t)(nf * 16 + m) * SEQ + t0 + kc * 32 + h * 8];

        // prefetch NEXT tile's K into dead kf registers
        if (it + 1 < ite) {
            const int t0n = t0 + 64;
#pragma unroll
            for (int tf = 0; tf < 4; ++tf)
#pragma unroll
                for (int kc = 0; kc < 2; ++kc)
                    kf[tf][kc] = *(const bf16x8*)
                        &Kg[base + (size_t)(t0n + tf * 16 + m) * HEAD_DIM + kc * 32 + h * 8];
        }

#pragma unroll
        for (int sub = 0; sub < 2; ++sub)
#pragma unroll
            for (int tf = 0; tf < 4; ++tf)
#pragma unroll
                for (int r = 0; r < 4; ++r) s[sub][tf][r] *= 0.125f;
        if (it == nt - 1) {
#pragma unroll
            for (int sub = 0; sub < 2; ++sub)
#pragma unroll
                for (int tf = 0; tf < 4; ++tf)
#pragma unroll
                    for (int r = 0; r < 4; ++r) {
                        int gq = q0 + sub * 16 + m;
                        int gt = t0 + tf * 16 + h * 4 + r;
                        if (gt > gq) s[sub][tf][r] = -__builtin_inff();
                    }
        }

        // ---- online softmax, per-lane row stats ----
#pragma unroll
        for (int sub = 0; sub < 2; ++sub) {
            float mx = s[sub][0][0];
#pragma unroll
            for (int tf = 0; tf < 4; ++tf)
#pragma unroll
                for (int r = 0; r < 4; ++r) mx = fmaxf(mx, s[sub][tf][r]);
            mx = fmaxf(mx, __shfl_xor(mx, 16));
            mx = fmaxf(mx, __shfl_xor(mx, 32));
            if (!__all(mx <= mrow[sub] + 8.f)) {
                float mn = fmaxf(mrow[sub], mx);
                float sf = __expf(mrow[sub] - mn);
                mrow[sub] = mn;
                lrow[sub] *= sf;
                float sfr[4];
#pragma unroll
                for (int r = 0; r < 4; ++r) sfr[r] = __shfl(sf, 20 * h + r);
#pragma unroll
                for (int nf = 0; nf < 4; ++nf)
#pragma unroll
                    for (int r = 0; r < 4; ++r) o[sub][nf][r] *= sfr[r];
            }
            float rs = 0.f;
#pragma unroll
            for (int tf = 0; tf < 4; ++tf)
#pragma unroll
                for (int r = 0; r < 4; ++r) {
                    float pv = __expf(s[sub][tf][r] - mrow[sub]);
                    s[sub][tf][r] = pv;
                    rs += pv;
                }
            rs += __shfl_xor(rs, 16);
            rs += __shfl_xor(rs, 32);
            lrow[sub] += rs;

            // pack P -> LDS: word (tf,rp) holds t={16tf+4h+2rp,+1} at (t/2)^swz
#pragma unroll
            for (int tf = 0; tf < 4; ++tf)
#pragma unroll
                for (int rp = 0; rp < 2; ++rp) {
                    unsigned int w = ((unsigned int)bfbits(s[sub][tf][2 * rp + 1]) << 16) |
                                     bfbits(s[sub][tf][2 * rp]);
                    Pk[wid][sub][m][(8 * tf + 2 * h + rp) ^ swz] = w;
                }
        }

        // ---- PV ----
        __builtin_amdgcn_s_setprio(1);
#pragma unroll
        for (int sub = 0; sub < 2; ++sub) {
#pragma unroll
            for (int kc = 0; kc < 2; ++kc) {
                bf16x8 ap = *(bf16x8*)&Pk[wid][sub][m][(16 * kc + 4 * h) ^ swz];
#pragma unroll
                for (int nf = 0; nf < 4; ++nf)
                    o[sub][nf] = __builtin_amdgcn_mfma_f32_16x16x32_bf16(
                        ap, vf[nf][kc], o[sub][nf], 0, 0, 0);
            }
        }
        __builtin_amdgcn_s_setprio(0);
    }

    // ---- split-K merge ----
    if (half == 1) {
#pragma unroll
        for (int sub = 0; sub < 2; ++sub) {
            Mg[pair][sub][lane] = mrow[sub];
            Lg[pair][sub][lane] = lrow[sub];
#pragma unroll
            for (int nf = 0; nf < 4; ++nf) Og[pair][sub][nf][lane] = o[sub][nf];
        }
    }
    __syncthreads();
    if (half == 0) {
        const int b_ = bh >> 4, hh = bh & 15;
#pragma unroll
        for (int sub = 0; sub < 2; ++sub) {
            float m1 = Mg[pair][sub][lane];
            float ms = fmaxf(mrow[sub], m1);
            float a0 = __expf(mrow[sub] - ms);
            float a1 = __expf(m1 - ms);
            float lc = lrow[sub] * a0 + Lg[pair][sub][lane] * a1;
            float a0r[4], a1r[4], lcr[4];
#pragma unroll
            for (int r = 0; r < 4; ++r) {
                a0r[r] = __shfl(a0, 20 * h + r);
                a1r[r] = __shfl(a1, 20 * h + r);
                lcr[r] = __shfl(lc, 20 * h + r);
            }
#pragma unroll
            for (int nf = 0; nf < 4; ++nf) {
                f32x4 o1 = Og[pair][sub][nf][lane];
#pragma unroll
                for (int r = 0; r < 4; ++r) {
                    float val = (o[sub][nf][r] * a0r[r] + o1[r] * a1r[r]) / lcr[r];
                    int s_ = q0 + sub * 16 + h * 4 + r;
                    AO[((size_t)(b_ * SEQ + s_)) * D_MODEL + hh * HEAD_DIM + nf * 16 + m] =
                        (bf16)val;
                }
            }
        }
    }
}

extern "C" void kernel_launch(void* const* d_in, const int* in_sizes, int n_in,
                              void* d_out, int out_size, void* d_ws, size_t ws_size,
                              hipStream_t stream) {
    const float* x  = (const float*)d_in[0];
    const float* Wq = (const float*)d_in[1];
    const float* bq = (const float*)d_in[2];
    const float* Wk = (const float*)d_in[3];
    const float* bk = (const float*)d_in[4];
    const float* Wv = (const float*)d_in[5];
    const float* bv = (const float*)d_in[6];
    const float* Wo = (const float*)d_in[7];
    const float* bo = (const float*)d_in[8];

    char* ws = (char*)d_ws;
    const size_t MB = 1u << 20;
    bf16* wt = (bf16*)ws;                  // 4 x [1024][1024] bf16 (QKV contiguous)
    bf16* xb = (bf16*)(ws + 8 * MB);       // [4096][1024] bf16
    bf16* Qb = (bf16*)(ws + 16 * MB);      // Q [32][2048][64]; K; V^T [32][64][2048]
    bf16* AO = (bf16*)(ws + 40 * MB);      // [4096][1024] bf16

    const size_t WSTRIDE = (size_t)D_MODEL * D_MODEL;

    cvt_x<<<dim3(MROWS * D_MODEL / 4 / 256), dim3(256), 0, stream>>>(x, xb);
    cvt_wt<<<dim3(32, 32, 4), dim3(32, 32), 0, stream>>>(Wq, Wk, Wv, Wo, wt);

    gemm_k<0><<<dim3(24, 32), dim3(256), 0, stream>>>(xb, wt, bq, bk, bv, Qb);

    bf16* Kb = Qb + 4194304;
    bf16* VTb = Qb + 2 * 4194304;
    attn_k<<<dim3(512), dim3(512), 0, stream>>>(Qb, Kb, VTb, AO);

    gemm_k<1><<<dim3(8, 32), dim3(256), 0, stream>>>(AO, wt + 3 * WSTRIDE, bo, bo, bo, d_out);
}